// Round 13
// baseline (43.761 us; speedup 1.0000x reference)
//
#include <hip/hip_runtime.h>

#define NEGINF (-__builtin_inff())
#define DETS 100
#define KEEP_CAP 100           // max survivors kept per class
#define SEG 128                // pool_box segment stride per class (pow2)
#define POOL_MAX 8192          // select LDS capacity (>= 80*KEEP_CAP total survivors)
#define CAND_MAX 1024          // max candidates per class (= N)

typedef unsigned long long u64;
typedef unsigned int u32;

__device__ __forceinline__ float bcastf(float v, int l) {
    return __uint_as_float(__builtin_amdgcn_readlane(__float_as_uint(v), l));
}
__device__ __forceinline__ u64 readlane64(u64 v, int l) {
    u32 lo = __builtin_amdgcn_readlane((u32)v, l);
    u32 hi = __builtin_amdgcn_readlane((u32)(v >> 32), l);
    return ((u64)hi << 32) | lo;
}

#define BOFF ((int)(0x3D4CCCCDu >> 18))   // bucket of 0.05f
__device__ __forceinline__ int score_bucket(u32 sb) {
    int b = (int)(sb >> 18) - BOFF;
    return (b < 0) ? 0 : (b > 255 ? 255 : b);
}

__device__ __forceinline__ float4 decode_box(const float* __restrict__ br4,
                                             float rx1, float ry1, float rx2, float ry2,
                                             float wmax, float hmax) {
    const float CLIP = 4.135166556742356f;  // log(1000/16)
    float w  = rx2 - rx1 + 1.0f;
    float h  = ry2 - ry1 + 1.0f;
    float cx = rx1 + 0.5f * w;
    float cy = ry1 + 0.5f * h;
    float dx = br4[0] / 10.0f;
    float dy = br4[1] / 10.0f;
    float dw = fminf(br4[2] / 5.0f, CLIP);
    float dh = fminf(br4[3] / 5.0f, CLIP);
    float pcx = dx * w + cx;
    float pcy = dy * h + cy;
    float pw  = expf(dw) * w;
    float ph  = expf(dh) * h;
    float4 b;
    b.x = fminf(fmaxf(pcx - 0.5f * pw, 0.0f), wmax);
    b.y = fminf(fmaxf(pcy - 0.5f * ph, 0.0f), hmax);
    b.z = fminf(fmaxf(pcx + 0.5f * pw - 1.0f, 0.0f), wmax);
    b.w = fminf(fmaxf(pcy + 0.5f * ph - 1.0f, 0.0f), hmax);
    return b;
}

// ---------------- k1: per-row softmax -> transposed score matrix (+ zero counters) ----------------
// 64 blocks x 4 waves x 4 consecutive rows: each block owns 16 consecutive rows -> every
// scoresT line is produced wholly by one block.
__global__ void __launch_bounds__(256)
k1_softmax_t(const float* __restrict__ logits, int C, int N,
             float* __restrict__ scoresT, u32* __restrict__ bcnt, u32* __restrict__ done_cnt) {
    if (blockIdx.x == 0) {
        bcnt[threadIdx.x] = 0;                  // zero 256 bucket counters
        if (threadIdx.x == 0) *done_cnt = 0;    // zero last-block ticket
    }

    int wave = threadIdx.x >> 6;
    int lane = threadIdx.x & 63;
    int base = blockIdx.x * 16 + wave * 4;

    #pragma unroll
    for (int rr = 0; rr < 4; ++rr) {
        int n = base + rr;
        if (n >= N) break;
        const float* row = logits + (size_t)n * C;

        float l0 = (lane < C) ? row[lane] : NEGINF;
        float l1 = (lane + 64 < C) ? row[lane + 64] : NEGINF;

        float m = fmaxf(l0, l1);
        #pragma unroll
        for (int o = 32; o; o >>= 1) m = fmaxf(m, __shfl_xor(m, o));

        float e0 = (lane < C) ? expf(l0 - m) : 0.0f;
        float e1 = (lane + 64 < C) ? expf(l1 - m) : 0.0f;
        float s = e0 + e1;
        #pragma unroll
        for (int o = 32; o; o >>= 1) s += __shfl_xor(s, o);

        if (lane >= 1 && lane < C)  scoresT[(size_t)(lane - 1) * N + n] = e0 / s;
        if (lane + 64 < C)          scoresT[(size_t)(lane + 63) * N + n] = e1 / s;
    }
}

// ---------------- k23: per-class NMS (wave 0) + last-done block runs the top-100 select ----------------
__global__ void __launch_bounds__(256)
k23_class_select(const float* __restrict__ boxreg, const float* __restrict__ refb,
                 const int* __restrict__ Hp, const int* __restrict__ Wp, int C, int N, int K,
                 const float* __restrict__ scoresT,
                 float* __restrict__ pool_box, u32* __restrict__ bcnt,
                 u64* __restrict__ bucket_keys, u32* __restrict__ bucket_idx, int BCAP,
                 u32* __restrict__ done_cnt, float* __restrict__ out) {
    __shared__ u64 sKey[POOL_MAX];               // NMS: keybuf[0..1023] | select: sort keys
    __shared__ u32 sIdx[POOL_MAX];               // NMS: b_l float4[0..1023] | select: idx
    __shared__ unsigned char keep_s[CAND_MAX];
    __shared__ int cum[257];
    __shared__ int s_B;
    __shared__ int s_fin;

    int k = blockIdx.x;      // 0..K-1
    int c = k + 1;           // class id
    int tid = threadIdx.x;
    int lane = tid & 63;

    // ================= phase 1: per-class NMS, wave 0 only (no returns before barrier) =================
    if (tid < 64) {
        const float* srow = scoresT + (size_t)k * N;
        volatile u64* keybuf = sKey;
        float4* b_l = reinterpret_cast<float4*>(sIdx);

        // prefetch all scores into registers (independent loads -> one latency wait)
        float pv[16];
        #pragma unroll
        for (int t = 0; t < 16; ++t) {
            int r = t * 64 + lane;
            pv[t] = (r < N) ? srow[r] : 0.0f;
        }

        // ballot compaction (ordered by n asc) into LDS keybuf
        int M = 0;
        #pragma unroll
        for (int t = 0; t < 16; ++t) {
            int r = t * 64 + lane;
            bool pass = pv[t] > 0.05f;
            u64 mask = __ballot(pass);
            if (pass) {
                int pos = M + __popcll(mask & ((1ull << lane) - 1ull));
                keybuf[pos] = ((u64)__float_as_uint(pv[t]) << 32) | (u32)(~(u32)r);
            }
            M += __popcll(mask);
        }
        __builtin_amdgcn_wave_barrier();

        float wmaxv = (float)(*Wp) - 1.0f;
        float hmaxv = (float)(*Hp) - 1.0f;

        if (M > 0 && M <= 128) {
            // ---------- register path: 2 sorted positions per lane ----------
            u64 k0 = (lane < M) ? keybuf[lane] : 0ull;
            u64 k1v = (64 + lane < M) ? keybuf[64 + lane] : 0ull;

            auto stage = [&](u64& key, int idx, int size, int stride) {
                u64 other = __shfl_xor(key, stride);
                bool up = ((idx & size) == 0);
                bool lower = ((idx & stride) == 0);
                bool want_max = (up == lower);
                if ((other > key) == want_max) key = other;
            };

            #pragma unroll 1
            for (int size = 2; size <= 64; size <<= 1) {
                #pragma unroll 1
                for (int stride = size >> 1; stride > 0; stride >>= 1) {
                    stage(k0, lane, size, stride);
                    stage(k1v, 64 + lane, size, stride);
                }
            }
            {   // size=128, stride=64: in-lane exchange
                u64 mx = (k0 > k1v) ? k0 : k1v;
                u64 mn = (k0 > k1v) ? k1v : k0;
                k0 = mx; k1v = mn;
            }
            #pragma unroll 1
            for (int stride = 32; stride > 0; stride >>= 1) {
                stage(k0, lane, 128, stride);
                stage(k1v, 64 + lane, 128, stride);
            }

            // decode (sorted position p0=lane, p1=64+lane)
            bool v0 = lane < M;
            bool v1 = (64 + lane) < M;
            float4 b0 = make_float4(0.f, 0.f, 0.f, 0.f);
            float4 b1 = make_float4(0.f, 0.f, 0.f, 0.f);
            if (v0) {
                int n = (int)(~(u32)k0);
                const float* rb = refb + (size_t)n * 4;
                const float* br = boxreg + (size_t)n * (4 * C) + (size_t)c * 4;
                b0 = decode_box(br, rb[0], rb[1], rb[2], rb[3], wmaxv, hmaxv);
            }
            if (v1) {
                int n = (int)(~(u32)k1v);
                const float* rb = refb + (size_t)n * 4;
                const float* br = boxreg + (size_t)n * (4 * C) + (size_t)c * 4;
                b1 = decode_box(br, rb[0], rb[1], rb[2], rb[3], wmaxv, hmaxv);
            }
            float a0 = (b0.z - b0.x + 1.0f) * (b0.w - b0.y + 1.0f);
            float a1 = (b1.z - b1.x + 1.0f) * (b1.w - b1.y + 1.0f);

            // suppression masks, split loops
            u64 m00 = 0, m01 = 0, m11 = 0;
            int M1 = (M < 64) ? M : 64;
            #pragma unroll 1
            for (int j = 1; j < M1; ++j) {
                float jx = bcastf(b0.x, j), jy = bcastf(b0.y, j);
                float jz = bcastf(b0.z, j), jw = bcastf(b0.w, j), ja = bcastf(a0, j);
                float iw = fminf(b0.z, jz) - fmaxf(b0.x, jx) + 1.0f;
                float ih = fminf(b0.w, jw) - fmaxf(b0.y, jy) + 1.0f;
                if (iw > 0.0f && ih > 0.0f) {
                    float inter = iw * ih;
                    float iou = inter / (a0 + ja - inter);
                    if (iou > 0.5f && j > lane) m00 |= 1ull << j;
                }
            }
            #pragma unroll 1
            for (int j = 64; j < M; ++j) {
                int l = j - 64;
                float jx = bcastf(b1.x, l), jy = bcastf(b1.y, l);
                float jz = bcastf(b1.z, l), jw = bcastf(b1.w, l), ja = bcastf(a1, l);
                {
                    float iw = fminf(b0.z, jz) - fmaxf(b0.x, jx) + 1.0f;
                    float ih = fminf(b0.w, jw) - fmaxf(b0.y, jy) + 1.0f;
                    if (iw > 0.0f && ih > 0.0f) {
                        float inter = iw * ih;
                        float iou = inter / (a0 + ja - inter);
                        if (iou > 0.5f) m01 |= 1ull << l;
                    }
                }
                {
                    float iw = fminf(b1.z, jz) - fmaxf(b1.x, jx) + 1.0f;
                    float ih = fminf(b1.w, jw) - fmaxf(b1.y, jy) + 1.0f;
                    if (iw > 0.0f && ih > 0.0f) {
                        float inter = iw * ih;
                        float iou = inter / (a1 + ja - inter);
                        if (iou > 0.5f && l > lane) m11 |= 1ull << l;
                    }
                }
            }

            // serial greedy scan, pure registers (uniform), split
            u64 sup0 = 0, sup1 = 0;
            int E1 = (M - 1 < 64) ? (M - 1) : 64;
            #pragma unroll 1
            for (int i = 0; i < E1; ++i) {
                if (!((sup0 >> i) & 1ull)) {
                    sup0 |= readlane64(m00, i);
                    sup1 |= readlane64(m01, i);
                }
            }
            #pragma unroll 1
            for (int i = 64; i < M - 1; ++i) {
                if (!((sup1 >> (i - 64)) & 1ull)) sup1 |= readlane64(m11, i - 64);
            }

            u64 vm0 = (M >= 64) ? ~0ull : ((1ull << M) - 1ull);
            u64 vm1 = (M > 64) ? ((M >= 128) ? ~0ull : ((1ull << (M - 64)) - 1ull)) : 0ull;
            u64 km0 = ~sup0 & vm0;
            u64 km1 = ~sup1 & vm1;
            int n0 = __popcll(km0);

            if (v0 && ((km0 >> lane) & 1ull)) {
                int rr = __popcll(km0 & ((1ull << lane) - 1ull));
                if (rr < KEEP_CAP) {
                    int pidx = k * SEG + rr;
                    pool_box[(size_t)pidx * 4 + 0] = b0.x;
                    pool_box[(size_t)pidx * 4 + 1] = b0.y;
                    pool_box[(size_t)pidx * 4 + 2] = b0.z;
                    pool_box[(size_t)pidx * 4 + 3] = b0.w;
                    u32 sb = (u32)(k0 >> 32);
                    int b = score_bucket(sb);
                    u32 slot = atomicAdd(&bcnt[b], 1u);
                    if ((int)slot < BCAP) {
                        bucket_keys[(size_t)b * BCAP + slot] = ((u64)sb << 32) | (u32)(~(u32)(k * N + lane));
                        bucket_idx [(size_t)b * BCAP + slot] = (u32)pidx;
                    }
                }
            }
            if (v1 && ((km1 >> lane) & 1ull)) {
                int rr = n0 + __popcll(km1 & ((1ull << lane) - 1ull));
                if (rr < KEEP_CAP) {
                    int pidx = k * SEG + rr;
                    pool_box[(size_t)pidx * 4 + 0] = b1.x;
                    pool_box[(size_t)pidx * 4 + 1] = b1.y;
                    pool_box[(size_t)pidx * 4 + 2] = b1.z;
                    pool_box[(size_t)pidx * 4 + 3] = b1.w;
                    u32 sb = (u32)(k1v >> 32);
                    int b = score_bucket(sb);
                    u32 slot = atomicAdd(&bcnt[b], 1u);
                    if ((int)slot < BCAP) {
                        bucket_keys[(size_t)b * BCAP + slot] = ((u64)sb << 32) | (u32)(~(u32)(k * N + 64 + lane));
                        bucket_idx [(size_t)b * BCAP + slot] = (u32)pidx;
                    }
                }
            }
        } else if (M > 128) {
            // ---------- slow path (practically never), wave-synchronous ----------
            int P2 = 64;
            while (P2 < M) P2 <<= 1;
            for (int i = M + lane; i < P2; i += 64) keybuf[i] = 0ull;
            __builtin_amdgcn_wave_barrier();

            #pragma unroll 1
            for (int size = 2; size <= P2; size <<= 1) {
                #pragma unroll 1
                for (int stride = size >> 1; stride > 0; stride >>= 1) {
                    for (int i = lane; i < P2; i += 64) {
                        int j = i ^ stride;
                        if (j > i) {
                            u64 ki = keybuf[i], kj = keybuf[j];
                            bool desc = ((i & size) == 0);
                            if (desc ? (kj > ki) : (ki > kj)) { keybuf[i] = kj; keybuf[j] = ki; }
                        }
                    }
                    __builtin_amdgcn_wave_barrier();
                }
            }

            for (int i = lane; i < M; i += 64) {
                int n = (int)(~(u32)keybuf[i]);
                const float* rb = refb + (size_t)n * 4;
                const float* br = boxreg + (size_t)n * (4 * C) + (size_t)c * 4;
                b_l[i] = decode_box(br, rb[0], rb[1], rb[2], rb[3], wmaxv, hmaxv);
                keep_s[i] = 1;
            }
            __builtin_amdgcn_wave_barrier();

            volatile unsigned char* keepf = keep_s;
            #pragma unroll 1
            for (int i = 0; i < M - 1; ++i) {
                if (!keepf[i]) continue;
                float4 bi = b_l[i];
                float ai = (bi.z - bi.x + 1.0f) * (bi.w - bi.y + 1.0f);
                for (int j = i + 1 + lane; j < M; j += 64) {
                    if (!keepf[j]) continue;
                    float4 bj = b_l[j];
                    float iw = fminf(bi.z, bj.z) - fmaxf(bi.x, bj.x) + 1.0f;
                    if (iw <= 0.0f) continue;
                    float ih = fminf(bi.w, bj.w) - fmaxf(bi.y, bj.y) + 1.0f;
                    if (ih <= 0.0f) continue;
                    float inter = iw * ih;
                    float aj = (bj.z - bj.x + 1.0f) * (bj.w - bj.y + 1.0f);
                    float iou = inter / (ai + aj - inter);
                    if (iou > 0.5f) keepf[j] = 0;
                }
                __builtin_amdgcn_wave_barrier();
            }
            __builtin_amdgcn_wave_barrier();

            int nch = (M + 63) >> 6;
            int r = 0;
            #pragma unroll 1
            for (int ch = 0; ch < nch; ++ch) {
                int j = ch * 64 + lane;
                bool kp = (j < M) && keepf[j];
                u64 mask = __ballot(kp);
                if (kp) {
                    int rr = r + __popcll(mask & ((1ull << lane) - 1ull));
                    if (rr < KEEP_CAP) {
                        int pidx = k * SEG + rr;
                        float4 b = b_l[j];
                        pool_box[(size_t)pidx * 4 + 0] = b.x;
                        pool_box[(size_t)pidx * 4 + 1] = b.y;
                        pool_box[(size_t)pidx * 4 + 2] = b.z;
                        pool_box[(size_t)pidx * 4 + 3] = b.w;
                        u32 sb = (u32)(keybuf[j] >> 32);
                        int bb = score_bucket(sb);
                        u32 slot = atomicAdd(&bcnt[bb], 1u);
                        if ((int)slot < BCAP) {
                            bucket_keys[(size_t)bb * BCAP + slot] = ((u64)sb << 32) | (u32)(~(u32)(k * N + j));
                            bucket_idx [(size_t)bb * BCAP + slot] = (u32)pidx;
                        }
                    }
                }
                r += __popcll(mask);
            }
        }
    }

    // ================= ticket: last finished block runs the select =================
    __syncthreads();
    if (tid == 0) {
        __threadfence();                       // release this block's pool/bucket writes
        u32 t = atomicAdd(done_cnt, 1u);
        s_fin = (t == (u32)(K - 1));
    }
    __syncthreads();
    if (!s_fin) return;
    __threadfence();                           // acquire all blocks' writes

    // ================= phase 2: gather top buckets + small sort + output (256 threads) =================
    {
        u64* key = sKey;
        int* idx = (int*)sIdx;

        int cl = (int)bcnt[tid];
        if (cl > BCAP) cl = BCAP;
        cum[tid] = cl;
        if (tid == 0) { cum[256] = 0; s_B = 0; }
        __syncthreads();

        // inclusive suffix scan: cum[b] = #entries in buckets >= b
        for (int off = 1; off < 256; off <<= 1) {
            int v = (tid + off < 256) ? cum[tid + off] : 0;
            __syncthreads();
            cum[tid] += v;
            __syncthreads();
        }
        int total = cum[0];

        if (total == 0) {
            if (tid < DETS) {
                out[tid] = 0.0f;
                out[DETS + tid * 4 + 0] = 0.0f;
                out[DETS + tid * 4 + 1] = 0.0f;
                out[DETS + tid * 4 + 2] = 0.0f;
                out[DETS + tid * 4 + 3] = 0.0f;
                out[DETS * 5 + tid] = 0.0f;
            }
            return;
        }

        int target = (total < DETS) ? total : DETS;
        if (cum[tid] >= target && cum[tid + 1] < target) s_B = tid;
        __syncthreads();
        int B = s_B;
        int S = cum[B];     // <= 80*KEEP_CAP = 8000 < POOL_MAX always

        // gather: thread t copies bucket t's entries to LDS at its disjoint offset
        if (tid >= B && cl > 0) {
            size_t gb = (size_t)tid * BCAP;
            int o = cum[tid] - cl;
            for (int e = 0; e < cl; ++e) {
                key[o + e] = bucket_keys[gb + e];
                idx[o + e] = (int)bucket_idx[gb + e];
            }
        }
        __syncthreads();

        int S2 = 128;
        while (S2 < S) S2 <<= 1;
        for (int i = S + tid; i < S2; i += 256) { key[i] = 0ull; idx[i] = -1; }

        // bitonic sort descending by key = (score desc, rank asc)
        for (int size = 2; size <= S2; size <<= 1) {
            for (int stride = size >> 1; stride > 0; stride >>= 1) {
                __syncthreads();
                for (int i = tid; i < S2; i += 256) {
                    int j = i ^ stride;
                    if (j > i) {
                        bool desc = ((i & size) == 0);
                        u64 ki = key[i], kj = key[j];
                        if (desc ? (kj > ki) : (ki > kj)) {
                            key[i] = kj; key[j] = ki;
                            int t = idx[i]; idx[i] = idx[j]; idx[j] = t;
                        }
                    }
                }
            }
        }
        __syncthreads();

        if (tid < DETS) {
            int it = tid;
            int id = (it < S) ? idx[it] : -1;
            if (id < 0) {
                out[it] = 0.0f;
                out[DETS + it * 4 + 0] = 0.0f;
                out[DETS + it * 4 + 1] = 0.0f;
                out[DETS + it * 4 + 2] = 0.0f;
                out[DETS + it * 4 + 3] = 0.0f;
                out[DETS * 5 + it] = 0.0f;
            } else {
                u64 kk = key[it];
                float s = __uint_as_float((u32)(kk >> 32));
                u32 rank = ~(u32)(kk & 0xFFFFFFFFull);
                out[it] = s;
                out[DETS + it * 4 + 0] = pool_box[(size_t)id * 4 + 0];
                out[DETS + it * 4 + 1] = pool_box[(size_t)id * 4 + 1];
                out[DETS + it * 4 + 2] = pool_box[(size_t)id * 4 + 2];
                out[DETS + it * 4 + 3] = pool_box[(size_t)id * 4 + 3];
                out[DETS * 5 + it] = (float)(rank / (u32)N + 1u);
            }
        }
    }
}

extern "C" void kernel_launch(void* const* d_in, const int* in_sizes, int n_in,
                              void* d_out, int out_size, void* d_ws, size_t ws_size,
                              hipStream_t stream) {
    const float* logits = (const float*)d_in[0];
    const float* boxreg = (const float*)d_in[1];
    const float* refb   = (const float*)d_in[2];
    const int*   Hp     = (const int*)d_in[3];
    const int*   Wp     = (const int*)d_in[4];
    float* out = (float*)d_out;

    int N = in_sizes[2] / 4;            // 1024
    int C = in_sizes[0] / N;            // 81
    int K = C - 1;                      // 80

    // workspace: bcnt[256] | done | scoresT[K*N] | pool_box[K*SEG*4] | bucket_keys[256*BCAP] | bucket_idx[256*BCAP]
    size_t fixed = 2048 + (size_t)K * N * 4 + (size_t)K * SEG * 16;
    int BCAP = 8192;                    // >= total survivors -> overflow impossible
    while (BCAP > 512 && fixed + (size_t)256 * BCAP * 12 > ws_size) BCAP >>= 1;

    char* w = (char*)d_ws;
    u32*   bcnt        = (u32*)w;
    u32*   done_cnt    = (u32*)(w + 1024);
    float* scoresT     = (float*)(w + 2048);
    float* pool_box    = (float*)(w + 2048 + (size_t)K * N * 4);
    u64*   bucket_keys = (u64*)(w + fixed);
    u32*   bucket_idx  = (u32*)(w + fixed + (size_t)256 * BCAP * 8);

    hipLaunchKernelGGL(k1_softmax_t, dim3((N + 15) / 16), dim3(256), 0, stream,
                       logits, C, N, scoresT, bcnt, done_cnt);
    hipLaunchKernelGGL(k23_class_select, dim3(K), dim3(256), 0, stream,
                       boxreg, refb, Hp, Wp, C, N, K, scoresT,
                       pool_box, bcnt, bucket_keys, bucket_idx, BCAP,
                       done_cnt, out);
}

// Round 14
// 42.479 us; speedup vs baseline: 1.0302x; 1.0302x over previous
//
#include <hip/hip_runtime.h>

#define NEGINF (-__builtin_inff())
#define DETS 100
#define KEEP_CAP 100           // max survivors kept per class
#define SEG 128                // pool_box segment stride per class (pow2)
#define POOL_MAX 8192          // k3 LDS capacity (>= 80*KEEP_CAP total survivors)
#define CAND_MAX 1024          // max candidates per class (= N)

typedef unsigned long long u64;
typedef unsigned int u32;

__device__ __forceinline__ float bcastf(float v, int l) {
    return __uint_as_float(__builtin_amdgcn_readlane(__float_as_uint(v), l));
}
__device__ __forceinline__ u64 readlane64(u64 v, int l) {
    u32 lo = __builtin_amdgcn_readlane((u32)v, l);
    u32 hi = __builtin_amdgcn_readlane((u32)(v >> 32), l);
    return ((u64)hi << 32) | lo;
}

#define BOFF ((int)(0x3D4CCCCDu >> 18))   // bucket of 0.05f
__device__ __forceinline__ int score_bucket(u32 sb) {
    int b = (int)(sb >> 18) - BOFF;
    return (b < 0) ? 0 : (b > 255 ? 255 : b);
}

__device__ __forceinline__ float4 decode_box(const float* __restrict__ br4,
                                             float rx1, float ry1, float rx2, float ry2,
                                             float wmax, float hmax) {
    const float CLIP = 4.135166556742356f;  // log(1000/16)
    float w  = rx2 - rx1 + 1.0f;
    float h  = ry2 - ry1 + 1.0f;
    float cx = rx1 + 0.5f * w;
    float cy = ry1 + 0.5f * h;
    float dx = br4[0] / 10.0f;
    float dy = br4[1] / 10.0f;
    float dw = fminf(br4[2] / 5.0f, CLIP);
    float dh = fminf(br4[3] / 5.0f, CLIP);
    float pcx = dx * w + cx;
    float pcy = dy * h + cy;
    float pw  = expf(dw) * w;
    float ph  = expf(dh) * h;
    float4 b;
    b.x = fminf(fmaxf(pcx - 0.5f * pw, 0.0f), wmax);
    b.y = fminf(fmaxf(pcy - 0.5f * ph, 0.0f), hmax);
    b.z = fminf(fmaxf(pcx + 0.5f * pw - 1.0f, 0.0f), wmax);
    b.w = fminf(fmaxf(pcy + 0.5f * ph - 1.0f, 0.0f), hmax);
    return b;
}

// ---------------- k1: per-row softmax -> transposed score matrix (+ zero buckets) ----------------
// 64 blocks x 4 waves x 4 consecutive rows: each block owns 16 consecutive rows, so every
// scoresT cache line is produced wholly by ONE block (no cross-XCD partial-line sharing).
__global__ void __launch_bounds__(256)
k1_softmax_t(const float* __restrict__ logits, int C, int N,
             float* __restrict__ scoresT, u32* __restrict__ bcnt) {
    if (blockIdx.x == 0) bcnt[threadIdx.x] = 0;   // zero 256 bucket counters (pre-k2 by stream order)

    int wave = threadIdx.x >> 6;
    int lane = threadIdx.x & 63;
    int base = blockIdx.x * 16 + wave * 4;

    #pragma unroll
    for (int rr = 0; rr < 4; ++rr) {
        int n = base + rr;
        if (n >= N) break;
        const float* row = logits + (size_t)n * C;

        float l0 = (lane < C) ? row[lane] : NEGINF;
        float l1 = (lane + 64 < C) ? row[lane + 64] : NEGINF;

        float m = fmaxf(l0, l1);
        #pragma unroll
        for (int o = 32; o; o >>= 1) m = fmaxf(m, __shfl_xor(m, o));

        float e0 = (lane < C) ? expf(l0 - m) : 0.0f;
        float e1 = (lane + 64 < C) ? expf(l1 - m) : 0.0f;
        float s = e0 + e1;
        #pragma unroll
        for (int o = 32; o; o >>= 1) s += __shfl_xor(s, o);

        if (lane >= 1 && lane < C)  scoresT[(size_t)(lane - 1) * N + n] = e0 / s;
        if (lane + 64 < C)          scoresT[(size_t)(lane + 63) * N + n] = e1 / s;
    }
}

// ---------------- k2: per-class compact + 128-wide register sort + bitmask NMS + bucket append ----------------
// Compact code (no sort unrolling): one wave, wave-synchronous, minimal I-footprint.
__global__ void __launch_bounds__(64)
k2_class(const float* __restrict__ boxreg, const float* __restrict__ refb,
         const int* __restrict__ Hp, const int* __restrict__ Wp, int C, int N,
         const float* __restrict__ scoresT,
         float* __restrict__ pool_box, u32* __restrict__ bcnt,
         u64* __restrict__ bucket_keys, u32* __restrict__ bucket_idx, int BCAP) {
    __shared__ u64 keybuf_s[CAND_MAX];
    __shared__ float4 b_l[CAND_MAX];        // slow path only
    __shared__ unsigned char keep_s[CAND_MAX];

    int k = blockIdx.x;      // 0..K-1
    int c = k + 1;           // class id
    int lane = threadIdx.x;  // 64 = 1 wave
    const float* srow = scoresT + (size_t)k * N;
    volatile u64* keybuf = keybuf_s;

    // prefetch all scores into registers (independent loads -> one latency wait)
    float pv[16];
    #pragma unroll
    for (int t = 0; t < 16; ++t) {
        int r = t * 64 + lane;
        pv[t] = (r < N) ? srow[r] : 0.0f;
    }

    // ballot compaction (ordered by n asc) into LDS keybuf
    int M = 0;
    #pragma unroll
    for (int t = 0; t < 16; ++t) {
        int r = t * 64 + lane;
        bool pass = pv[t] > 0.05f;
        u64 mask = __ballot(pass);
        if (pass) {
            int pos = M + __popcll(mask & ((1ull << lane) - 1ull));
            keybuf[pos] = ((u64)__float_as_uint(pv[t]) << 32) | (u32)(~(u32)r);
        }
        M += __popcll(mask);
    }
    __builtin_amdgcn_wave_barrier();

    if (M == 0) return;

    float wmaxv = (float)(*Wp) - 1.0f;
    float hmaxv = (float)(*Hp) - 1.0f;

    if (M <= 128) {
        // ---------- register path: 2 sorted positions per lane ----------
        u64 k0 = (lane < M) ? keybuf[lane] : 0ull;
        u64 k1v = (64 + lane < M) ? keybuf[64 + lane] : 0ull;

        auto stage = [&](u64& key, int idx, int size, int stride) {
            u64 other = __shfl_xor(key, stride);
            bool up = ((idx & size) == 0);
            bool lower = ((idx & stride) == 0);
            bool want_max = (up == lower);
            if ((other > key) == want_max) key = other;
        };

        #pragma unroll 1
        for (int size = 2; size <= 64; size <<= 1) {
            #pragma unroll 1
            for (int stride = size >> 1; stride > 0; stride >>= 1) {
                stage(k0, lane, size, stride);
                stage(k1v, 64 + lane, size, stride);
            }
        }
        {   // size=128, stride=64: in-lane exchange
            u64 mx = (k0 > k1v) ? k0 : k1v;
            u64 mn = (k0 > k1v) ? k1v : k0;
            k0 = mx; k1v = mn;
        }
        #pragma unroll 1
        for (int stride = 32; stride > 0; stride >>= 1) {
            stage(k0, lane, 128, stride);
            stage(k1v, 64 + lane, 128, stride);
        }

        // decode (sorted position p0=lane, p1=64+lane)
        bool v0 = lane < M;
        bool v1 = (64 + lane) < M;
        float4 b0 = make_float4(0.f, 0.f, 0.f, 0.f);
        float4 b1 = make_float4(0.f, 0.f, 0.f, 0.f);
        if (v0) {
            int n = (int)(~(u32)k0);
            const float* rb = refb + (size_t)n * 4;
            const float* br = boxreg + (size_t)n * (4 * C) + (size_t)c * 4;
            b0 = decode_box(br, rb[0], rb[1], rb[2], rb[3], wmaxv, hmaxv);
        }
        if (v1) {
            int n = (int)(~(u32)k1v);
            const float* rb = refb + (size_t)n * 4;
            const float* br = boxreg + (size_t)n * (4 * C) + (size_t)c * 4;
            b1 = decode_box(br, rb[0], rb[1], rb[2], rb[3], wmaxv, hmaxv);
        }
        float a0 = (b0.z - b0.x + 1.0f) * (b0.w - b0.y + 1.0f);
        float a1 = (b1.z - b1.x + 1.0f) * (b1.w - b1.y + 1.0f);

        // suppression masks, split loops (j in boxes 0..63, then 64..M-1)
        u64 m00 = 0, m01 = 0, m11 = 0;
        int M1 = (M < 64) ? M : 64;
        #pragma unroll 1
        for (int j = 1; j < M1; ++j) {
            float jx = bcastf(b0.x, j), jy = bcastf(b0.y, j);
            float jz = bcastf(b0.z, j), jw = bcastf(b0.w, j), ja = bcastf(a0, j);
            float iw = fminf(b0.z, jz) - fmaxf(b0.x, jx) + 1.0f;
            float ih = fminf(b0.w, jw) - fmaxf(b0.y, jy) + 1.0f;
            if (iw > 0.0f && ih > 0.0f) {
                float inter = iw * ih;
                float iou = inter / (a0 + ja - inter);
                if (iou > 0.5f && j > lane) m00 |= 1ull << j;
            }
        }
        #pragma unroll 1
        for (int j = 64; j < M; ++j) {
            int l = j - 64;
            float jx = bcastf(b1.x, l), jy = bcastf(b1.y, l);
            float jz = bcastf(b1.z, l), jw = bcastf(b1.w, l), ja = bcastf(a1, l);
            {   // box0 vs j (j >= 64 > lane always)
                float iw = fminf(b0.z, jz) - fmaxf(b0.x, jx) + 1.0f;
                float ih = fminf(b0.w, jw) - fmaxf(b0.y, jy) + 1.0f;
                if (iw > 0.0f && ih > 0.0f) {
                    float inter = iw * ih;
                    float iou = inter / (a0 + ja - inter);
                    if (iou > 0.5f) m01 |= 1ull << l;
                }
            }
            {   // box1 vs j
                float iw = fminf(b1.z, jz) - fmaxf(b1.x, jx) + 1.0f;
                float ih = fminf(b1.w, jw) - fmaxf(b1.y, jy) + 1.0f;
                if (iw > 0.0f && ih > 0.0f) {
                    float inter = iw * ih;
                    float iou = inter / (a1 + ja - inter);
                    if (iou > 0.5f && l > lane) m11 |= 1ull << l;
                }
            }
        }

        // serial greedy scan, pure registers (uniform), split
        u64 sup0 = 0, sup1 = 0;
        int E1 = (M - 1 < 64) ? (M - 1) : 64;
        #pragma unroll 1
        for (int i = 0; i < E1; ++i) {
            if (!((sup0 >> i) & 1ull)) {
                sup0 |= readlane64(m00, i);
                sup1 |= readlane64(m01, i);
            }
        }
        #pragma unroll 1
        for (int i = 64; i < M - 1; ++i) {
            if (!((sup1 >> (i - 64)) & 1ull)) sup1 |= readlane64(m11, i - 64);
        }

        u64 vm0 = (M >= 64) ? ~0ull : ((1ull << M) - 1ull);
        u64 vm1 = (M > 64) ? ((M >= 128) ? ~0ull : ((1ull << (M - 64)) - 1ull)) : 0ull;
        u64 km0 = ~sup0 & vm0;
        u64 km1 = ~sup1 & vm1;
        int n0 = __popcll(km0);

        if (v0 && ((km0 >> lane) & 1ull)) {
            int rr = __popcll(km0 & ((1ull << lane) - 1ull));
            if (rr < KEEP_CAP) {
                int pidx = k * SEG + rr;
                pool_box[(size_t)pidx * 4 + 0] = b0.x;
                pool_box[(size_t)pidx * 4 + 1] = b0.y;
                pool_box[(size_t)pidx * 4 + 2] = b0.z;
                pool_box[(size_t)pidx * 4 + 3] = b0.w;
                u32 sb = (u32)(k0 >> 32);
                int b = score_bucket(sb);
                u32 slot = atomicAdd(&bcnt[b], 1u);
                if ((int)slot < BCAP) {
                    bucket_keys[(size_t)b * BCAP + slot] = ((u64)sb << 32) | (u32)(~(u32)(k * N + lane));
                    bucket_idx [(size_t)b * BCAP + slot] = (u32)pidx;
                }
            }
        }
        if (v1 && ((km1 >> lane) & 1ull)) {
            int rr = n0 + __popcll(km1 & ((1ull << lane) - 1ull));
            if (rr < KEEP_CAP) {
                int pidx = k * SEG + rr;
                pool_box[(size_t)pidx * 4 + 0] = b1.x;
                pool_box[(size_t)pidx * 4 + 1] = b1.y;
                pool_box[(size_t)pidx * 4 + 2] = b1.z;
                pool_box[(size_t)pidx * 4 + 3] = b1.w;
                u32 sb = (u32)(k1v >> 32);
                int b = score_bucket(sb);
                u32 slot = atomicAdd(&bcnt[b], 1u);
                if ((int)slot < BCAP) {
                    bucket_keys[(size_t)b * BCAP + slot] = ((u64)sb << 32) | (u32)(~(u32)(k * N + 64 + lane));
                    bucket_idx [(size_t)b * BCAP + slot] = (u32)pidx;
                }
            }
        }
        return;
    }

    // ---------- slow path (M > 128, practically never), wave-synchronous ----------
    {
        int P2 = 64;
        while (P2 < M) P2 <<= 1;
        for (int i = M + lane; i < P2; i += 64) keybuf[i] = 0ull;
        __builtin_amdgcn_wave_barrier();

        #pragma unroll 1
        for (int size = 2; size <= P2; size <<= 1) {
            #pragma unroll 1
            for (int stride = size >> 1; stride > 0; stride >>= 1) {
                for (int i = lane; i < P2; i += 64) {
                    int j = i ^ stride;
                    if (j > i) {
                        u64 ki = keybuf[i], kj = keybuf[j];
                        bool desc = ((i & size) == 0);
                        if (desc ? (kj > ki) : (ki > kj)) { keybuf[i] = kj; keybuf[j] = ki; }
                    }
                }
                __builtin_amdgcn_wave_barrier();
            }
        }

        for (int i = lane; i < M; i += 64) {
            int n = (int)(~(u32)keybuf[i]);
            const float* rb = refb + (size_t)n * 4;
            const float* br = boxreg + (size_t)n * (4 * C) + (size_t)c * 4;
            b_l[i] = decode_box(br, rb[0], rb[1], rb[2], rb[3], wmaxv, hmaxv);
            keep_s[i] = 1;
        }
        __builtin_amdgcn_wave_barrier();

        volatile unsigned char* keepf = keep_s;
        #pragma unroll 1
        for (int i = 0; i < M - 1; ++i) {
            if (!keepf[i]) continue;
            float4 bi = b_l[i];
            float ai = (bi.z - bi.x + 1.0f) * (bi.w - bi.y + 1.0f);
            for (int j = i + 1 + lane; j < M; j += 64) {
                if (!keepf[j]) continue;
                float4 bj = b_l[j];
                float iw = fminf(bi.z, bj.z) - fmaxf(bi.x, bj.x) + 1.0f;
                if (iw <= 0.0f) continue;
                float ih = fminf(bi.w, bj.w) - fmaxf(bi.y, bj.y) + 1.0f;
                if (ih <= 0.0f) continue;
                float inter = iw * ih;
                float aj = (bj.z - bj.x + 1.0f) * (bj.w - bj.y + 1.0f);
                float iou = inter / (ai + aj - inter);
                if (iou > 0.5f) keepf[j] = 0;
            }
            __builtin_amdgcn_wave_barrier();
        }
        __builtin_amdgcn_wave_barrier();

        int nch = (M + 63) >> 6;
        int r = 0;
        #pragma unroll 1
        for (int ch = 0; ch < nch; ++ch) {
            int j = ch * 64 + lane;
            bool kp = (j < M) && keepf[j];
            u64 mask = __ballot(kp);
            if (kp) {
                int rr = r + __popcll(mask & ((1ull << lane) - 1ull));
                if (rr < KEEP_CAP) {
                    int pidx = k * SEG + rr;
                    float4 b = b_l[j];
                    pool_box[(size_t)pidx * 4 + 0] = b.x;
                    pool_box[(size_t)pidx * 4 + 1] = b.y;
                    pool_box[(size_t)pidx * 4 + 2] = b.z;
                    pool_box[(size_t)pidx * 4 + 3] = b.w;
                    u32 sb = (u32)(keybuf[j] >> 32);
                    int bb = score_bucket(sb);
                    u32 slot = atomicAdd(&bcnt[bb], 1u);
                    if ((int)slot < BCAP) {
                        bucket_keys[(size_t)bb * BCAP + slot] = ((u64)sb << 32) | (u32)(~(u32)(k * N + j));
                        bucket_idx [(size_t)bb * BCAP + slot] = (u32)pidx;
                    }
                }
            }
            r += __popcll(mask);
        }
    }
}

// ---------------- k3: gather top buckets (parallel by flat position) + small sort + output ----------------
__global__ void __launch_bounds__(256)
k3_select(const u32* __restrict__ bcnt, const u64* __restrict__ bucket_keys,
          const u32* __restrict__ bucket_idx, const float* __restrict__ pool_box,
          int N, int BCAP, float* __restrict__ out) {
    __shared__ u64 key[POOL_MAX];
    __shared__ int idx[POOL_MAX];
    __shared__ int cum[257];
    __shared__ int s_B;

    int tid = threadIdx.x;  // 256 threads; thread t owns bucket t
    int cl = (int)bcnt[tid];
    if (cl > BCAP) cl = BCAP;
    cum[tid] = cl;
    if (tid == 0) { cum[256] = 0; s_B = 0; }
    __syncthreads();

    // inclusive suffix scan: cum[b] = #entries in buckets >= b  (so bucket b occupies [cum[b+1], cum[b]))
    for (int off = 1; off < 256; off <<= 1) {
        int v = (tid + off < 256) ? cum[tid + off] : 0;
        __syncthreads();
        cum[tid] += v;
        __syncthreads();
    }
    int total = cum[0];

    if (total == 0) {
        if (tid < DETS) {
            out[tid] = 0.0f;
            out[DETS + tid * 4 + 0] = 0.0f;
            out[DETS + tid * 4 + 1] = 0.0f;
            out[DETS + tid * 4 + 2] = 0.0f;
            out[DETS + tid * 4 + 3] = 0.0f;
            out[DETS * 5 + tid] = 0.0f;
        }
        return;
    }

    int target = (total < DETS) ? total : DETS;
    if (cum[tid] >= target && cum[tid + 1] < target) s_B = tid;
    __syncthreads();
    int B = s_B;
    int S = cum[B];     // <= 80*KEEP_CAP = 8000 < POOL_MAX always

    // parallel gather: flat position p -> bucket b via binary search (cum[b] > p >= cum[b+1])
    for (int p = tid; p < S; p += 256) {
        int lo = B, hi = 255;            // cum[B] = S > p, so lo valid
        while (lo < hi) {
            int mid = (lo + hi + 1) >> 1;
            if (cum[mid] > p) lo = mid; else hi = mid - 1;
        }
        int b = lo;
        int e = p - cum[b + 1];
        key[p] = bucket_keys[(size_t)b * BCAP + e];
        idx[p] = (int)bucket_idx[(size_t)b * BCAP + e];
    }
    __syncthreads();

    int S2 = 128;
    while (S2 < S) S2 <<= 1;
    for (int i = S + tid; i < S2; i += 256) { key[i] = 0ull; idx[i] = -1; }

    // bitonic sort descending by key = (score desc, rank asc)
    for (int size = 2; size <= S2; size <<= 1) {
        for (int stride = size >> 1; stride > 0; stride >>= 1) {
            __syncthreads();
            for (int i = tid; i < S2; i += 256) {
                int j = i ^ stride;
                if (j > i) {
                    bool desc = ((i & size) == 0);
                    u64 ki = key[i], kj = key[j];
                    if (desc ? (kj > ki) : (ki > kj)) {
                        key[i] = kj; key[j] = ki;
                        int t = idx[i]; idx[i] = idx[j]; idx[j] = t;
                    }
                }
            }
        }
    }
    __syncthreads();

    if (tid < DETS) {
        int it = tid;
        int id = (it < S) ? idx[it] : -1;
        if (id < 0) {
            out[it] = 0.0f;
            out[DETS + it * 4 + 0] = 0.0f;
            out[DETS + it * 4 + 1] = 0.0f;
            out[DETS + it * 4 + 2] = 0.0f;
            out[DETS + it * 4 + 3] = 0.0f;
            out[DETS * 5 + it] = 0.0f;
        } else {
            u64 kk = key[it];
            float s = __uint_as_float((u32)(kk >> 32));
            u32 rank = ~(u32)(kk & 0xFFFFFFFFull);
            out[it] = s;
            out[DETS + it * 4 + 0] = pool_box[(size_t)id * 4 + 0];
            out[DETS + it * 4 + 1] = pool_box[(size_t)id * 4 + 1];
            out[DETS + it * 4 + 2] = pool_box[(size_t)id * 4 + 2];
            out[DETS + it * 4 + 3] = pool_box[(size_t)id * 4 + 3];
            out[DETS * 5 + it] = (float)(rank / (u32)N + 1u);
        }
    }
}

extern "C" void kernel_launch(void* const* d_in, const int* in_sizes, int n_in,
                              void* d_out, int out_size, void* d_ws, size_t ws_size,
                              hipStream_t stream) {
    const float* logits = (const float*)d_in[0];
    const float* boxreg = (const float*)d_in[1];
    const float* refb   = (const float*)d_in[2];
    const int*   Hp     = (const int*)d_in[3];
    const int*   Wp     = (const int*)d_in[4];
    float* out = (float*)d_out;

    int N = in_sizes[2] / 4;            // 1024
    int C = in_sizes[0] / N;            // 81
    int K = C - 1;                      // 80

    // workspace: bcnt[256] | scoresT[K*N] | pool_box[K*SEG*4] | bucket_keys[256*BCAP] | bucket_idx[256*BCAP]
    size_t fixed = 1024 + (size_t)K * N * 4 + (size_t)K * SEG * 16;
    int BCAP = 8192;                    // >= total survivors -> overflow impossible
    while (BCAP > 512 && fixed + (size_t)256 * BCAP * 12 > ws_size) BCAP >>= 1;

    char* w = (char*)d_ws;
    u32*   bcnt        = (u32*)w;
    float* scoresT     = (float*)(w + 1024);
    float* pool_box    = (float*)(w + 1024 + (size_t)K * N * 4);
    u64*   bucket_keys = (u64*)(w + fixed);
    u32*   bucket_idx  = (u32*)(w + fixed + (size_t)256 * BCAP * 8);

    hipLaunchKernelGGL(k1_softmax_t, dim3((N + 15) / 16), dim3(256), 0, stream,
                       logits, C, N, scoresT, bcnt);
    hipLaunchKernelGGL(k2_class, dim3(K), dim3(64), 0, stream,
                       boxreg, refb, Hp, Wp, C, N, scoresT,
                       pool_box, bcnt, bucket_keys, bucket_idx, BCAP);
    hipLaunchKernelGGL(k3_select, dim3(1), dim3(256), 0, stream,
                       bcnt, bucket_keys, bucket_idx, pool_box, N, BCAP, out);
}